// Round 3
// baseline (587.655 us; speedup 1.0000x reference)
//
#include <hip/hip_runtime.h>
#include <hip/hip_bf16.h>

// Problem constants
#define BATCH   65536
#define HW      28
#define OHW     26
#define FEAT    676     // 26*26
#define KPAD    704     // 22 chunks of 32
#define FPAD    712     // feat row stride in ushorts (global AND LDS; 356 dwords, !=0 mod 32 in quads -> 2-way A-read aliasing only)
#define FQUAD   (FPAD / 8)   // 89 float4 per row
#define HID     200
#define NCLS    10
#define CMT     8       // images per conv block
#define GMT     32      // rows per gemm block
#define XSTRIDE 788     // xs LDS row stride (floats): %4==0 for b128 align; conflict-engineered

typedef __attribute__((ext_vector_type(8))) __bf16 bf16x8;
typedef __attribute__((ext_vector_type(4))) float  f32x4;

// ---------------------------------------------------------------------------
// prep: w1 (676x200 f32 row-major) -> w1tf bf16 in MFMA B-fragment order.
// element e = ((kc*13 + nt)*64 + lane)*8 + j ; n = nt*16+(lane&15), k = kc*32+(lane>>4)*8+j
// => a wave's B-load for (kc,nt) is 64 lanes x 16B CONTIGUOUS (1 KB, fully coalesced).
// ---------------------------------------------------------------------------
__global__ __launch_bounds__(256) void prep_w1tf(const float* __restrict__ w1,
                                                 unsigned short* __restrict__ w1tf) {
  int idx = blockIdx.x * 256 + threadIdx.x;
  if (idx >= 22 * 13 * 64 * 8) return;
  int j    = idx & 7;
  int lane = (idx >> 3) & 63;
  int fi   = idx >> 9;          // kc*13 + nt
  int nt   = fi % 13;
  int kc   = fi / 13;
  int n = nt * 16 + (lane & 15);
  int k = kc * 32 + (lane >> 4) * 8 + j;
  float v = (n < HID && k < FEAT) ? w1[k * HID + n] : 0.f;
  __hip_bfloat16 h = __float2bfloat16(v);
  w1tf[idx] = __builtin_bit_cast(unsigned short, h);
}

// ---------------------------------------------------------------------------
// conv_k: x -> bf16 feat (712-padded rows) in d_ws. All global traffic coalesced.
// ---------------------------------------------------------------------------
__global__ __launch_bounds__(256, 4) void conv_k(const float* __restrict__ x,
                                                 const float* __restrict__ cwp,
                                                 unsigned short* __restrict__ featg) {
  __shared__ float xs[CMT][XSTRIDE];             // 25,216 B
  __shared__ unsigned short feat[CMT][FPAD];     // 11,392 B  -> 36.6 KB, 4 blk/CU
  const int tid = threadIdx.x;

  float cw[9];
  #pragma unroll
  for (int t = 0; t < 9; ++t) cw[t] = cwp[t];

  // stage x coalesced: 8 images x 196 float4, flat over the block's contiguous x
  const float4* xg = (const float4*)(x + (size_t)blockIdx.x * CMT * (HW * HW));
  for (int idx = tid; idx < CMT * 196; idx += 256) {
    int m = idx / 196, q = idx - m * 196;
    float4 v = xg[idx];
    *(float4*)&xs[m][q * 4] = v;
  }
  // zero feat pad cols [676, 712) : 18 dwords x 8 rows
  if (tid < CMT * 18) {
    int m = tid / 18, d = tid - m * 18;
    ((unsigned int*)&feat[m][0])[338 + d] = 0u;
  }
  __syncthreads();

  // conv 3x3 VALID from LDS; task = (m, i, half-row). 416 tasks.
  for (int t0 = tid; t0 < CMT * OHW * 2; t0 += 256) {
    int m = t0 & 7;
    int s = t0 >> 3;           // 0..51
    int i = s >> 1;            // out row
    int h = s & 1;             // half
    int cbase = h ? 12 : 0;    // first staged input col
    float r[3][16];
    #pragma unroll
    for (int di = 0; di < 3; ++di) {
      #pragma unroll
      for (int q = 0; q < 4; ++q) {
        float4 v = *(const float4*)&xs[m][(i + di) * HW + cbase + q * 4];
        r[di][q * 4 + 0] = v.x; r[di][q * 4 + 1] = v.y;
        r[di][q * 4 + 2] = v.z; r[di][q * 4 + 3] = v.w;
      }
    }
    // h=0: outputs j=0..13 (7 pairs); h=1: outputs j=14..25 (6 pairs)
    int np    = 7 - h;
    int jw0   = h ? 14 : 0;
    unsigned int* dst = (unsigned int*)&feat[m][i * OHW + jw0];   // even col -> aligned
    #pragma unroll
    for (int p = 0; p < 7; ++p) {
      if (p < np) {
        int c0 = (jw0 + 2 * p) - cbase;     // local col of first tap
        float s0 = 0.f, s1 = 0.f;
        #pragma unroll
        for (int di = 0; di < 3; ++di) {
          #pragma unroll
          for (int dj = 0; dj < 3; ++dj) {
            s0 += cw[di * 3 + dj] * r[di][c0 + dj];
            s1 += cw[di * 3 + dj] * r[di][c0 + 1 + dj];
          }
        }
        __hip_bfloat16 h0 = __float2bfloat16(s0);
        __hip_bfloat16 h1 = __float2bfloat16(s1);
        dst[p] = (unsigned int)__builtin_bit_cast(unsigned short, h0)
               | ((unsigned int)__builtin_bit_cast(unsigned short, h1) << 16);
      }
    }
  }
  __syncthreads();

  // flat coalesced store: LDS feat layout == global layout (both 712-stride)
  float4* fg = (float4*)featg + (size_t)blockIdx.x * (CMT * FQUAD);
  const float4* fl = (const float4*)&feat[0][0];
  for (int idx = tid; idx < CMT * FQUAD; idx += 256) fg[idx] = fl[idx];
}

// ---------------------------------------------------------------------------
// gemm_k: out = relu(feat @ w1 + b1) @ w2 + b2 ; MFMA 16x16x32 bf16
// A: lane ln holds rows {ln, 16+ln}; C/D: col=lane&15, row=(lane>>4)*4+reg (m89/m91)
// ---------------------------------------------------------------------------
template<int NT0, int NT>
__device__ __forceinline__ void gemm_slice(
    const unsigned short (*featT)[FPAD], const unsigned short* __restrict__ w1tf,
    const float* __restrict__ b1, const float* __restrict__ w2,
    float (*pbuf)[GMT][NCLS], int wave, int lane) {
  const int ln = lane & 15;
  const int qd = lane >> 4;
  f32x4 acc0[NT], acc1[NT];
  #pragma unroll
  for (int t = 0; t < NT; ++t) {
    acc0[t] = (f32x4){0.f, 0.f, 0.f, 0.f};
    acc1[t] = (f32x4){0.f, 0.f, 0.f, 0.f};
  }
  const int koff = qd * 8;
  for (int kc = 0; kc < 22; ++kc) {
    const int k0 = kc * 32 + koff;
    bf16x8 a0 = *(const bf16x8*)&featT[ln][k0];
    bf16x8 a1 = *(const bf16x8*)&featT[16 + ln][k0];
    #pragma unroll
    for (int t = 0; t < NT; ++t) {
      bf16x8 b = *(const bf16x8*)(w1tf + ((size_t)(kc * 13 + NT0 + t) * 64 + lane) * 8);
      acc0[t] = __builtin_amdgcn_mfma_f32_16x16x32_bf16(a0, b, acc0[t], 0, 0, 0);
      acc1[t] = __builtin_amdgcn_mfma_f32_16x16x32_bf16(a1, b, acc1[t], 0, 0, 0);
    }
  }
  // epilogue per m-half: relu + in-register GEMM2 partials + 16-lane reduce
  #pragma unroll
  for (int mh = 0; mh < 2; ++mh) {
    float partial[4][NCLS];
    #pragma unroll
    for (int rr = 0; rr < 4; ++rr)
      #pragma unroll
      for (int c = 0; c < NCLS; ++c) partial[rr][c] = 0.f;
    #pragma unroll
    for (int t = 0; t < NT; ++t) {
      const int n = (NT0 + t) * 16 + ln;
      if (n < HID) {
        const float bias = b1[n];
        const float2* w2r = (const float2*)(w2 + n * NCLS);
        float2 wv[5];
        #pragma unroll
        for (int p = 0; p < 5; ++p) wv[p] = w2r[p];
        const f32x4 a = mh ? acc1[t] : acc0[t];
        #pragma unroll
        for (int rr = 0; rr < 4; ++rr) {
          const float hd = fmaxf(a[rr] + bias, 0.f);
          #pragma unroll
          for (int p = 0; p < 5; ++p) {
            partial[rr][2 * p]     += hd * wv[p].x;
            partial[rr][2 * p + 1] += hd * wv[p].y;
          }
        }
      }
    }
    #pragma unroll
    for (int rr = 0; rr < 4; ++rr) {
      #pragma unroll
      for (int c = 0; c < NCLS; ++c) {
        float v = partial[rr][c];
        v += __shfl_xor(v, 1, 16);
        v += __shfl_xor(v, 2, 16);
        v += __shfl_xor(v, 4, 16);
        v += __shfl_xor(v, 8, 16);
        if (ln == 0) pbuf[wave][mh * 16 + qd * 4 + rr][c] = v;
      }
    }
  }
}

__global__ __launch_bounds__(256, 3) void gemm_k(
    const unsigned short* __restrict__ featg, const unsigned short* __restrict__ w1tf,
    const float* __restrict__ b1, const float* __restrict__ w2,
    const float* __restrict__ b2, float* __restrict__ out) {
  __shared__ unsigned short featT[GMT][FPAD];   // 45,568 B
  __shared__ float pbuf[4][GMT][NCLS];          //  5,120 B -> 50.7 KB, 3 blk/CU
  const int tid  = threadIdx.x;
  const int wave = tid >> 6;
  const int lane = tid & 63;

  // stage feat tile coalesced (flat: global layout == LDS layout, 712-stride)
  const float4* g4 = (const float4*)featg + (size_t)blockIdx.x * (GMT * FQUAD);
  float4* l4 = (float4*)&featT[0][0];
  for (int idx = tid; idx < GMT * FQUAD; idx += 256) l4[idx] = g4[idx];  // 2848 quads
  __syncthreads();

  switch (wave) {
    case 0:  gemm_slice<0, 4>(featT, w1tf, b1, w2, pbuf, wave, lane); break;
    case 1:  gemm_slice<4, 3>(featT, w1tf, b1, w2, pbuf, wave, lane); break;
    case 2:  gemm_slice<7, 3>(featT, w1tf, b1, w2, pbuf, wave, lane); break;
    default: gemm_slice<10, 3>(featT, w1tf, b1, w2, pbuf, wave, lane); break;
  }
  __syncthreads();

  for (int o = tid; o < GMT * NCLS; o += 256) {   // 320 outputs
    int m = o / NCLS, c = o - m * NCLS;
    float s = pbuf[0][m][c] + pbuf[1][m][c] + pbuf[2][m][c] + pbuf[3][m][c] + b2[c];
    out[(size_t)blockIdx.x * (GMT * NCLS) + o] = s;
  }
}

// ---------------------------------------------------------------------------
// Fallback (small ws): round-2 fused kernel, upgraded to fragment-ordered B.
// ---------------------------------------------------------------------------
#define FMT 16
template<int NT0, int NT>
__device__ __forceinline__ void fgemm_epi(
    const unsigned short (*feat)[FPAD], const unsigned short* __restrict__ w1tf,
    const float* __restrict__ b1, const float* __restrict__ w2,
    float (*pbuf)[FMT][NCLS], int wave, int lane) {
  const int ln = lane & 15, qd = lane >> 4;
  f32x4 acc[NT];
  #pragma unroll
  for (int t = 0; t < NT; ++t) acc[t] = (f32x4){0.f, 0.f, 0.f, 0.f};
  const int koff = qd * 8;
  for (int kc = 0; kc < 22; ++kc) {
    const int k0 = kc * 32 + koff;
    bf16x8 a = *(const bf16x8*)&feat[ln][k0];
    #pragma unroll
    for (int t = 0; t < NT; ++t) {
      bf16x8 b = *(const bf16x8*)(w1tf + ((size_t)(kc * 13 + NT0 + t) * 64 + lane) * 8);
      acc[t] = __builtin_amdgcn_mfma_f32_16x16x32_bf16(a, b, acc[t], 0, 0, 0);
    }
  }
  float partial[4][NCLS];
  #pragma unroll
  for (int rr = 0; rr < 4; ++rr)
    #pragma unroll
    for (int c = 0; c < NCLS; ++c) partial[rr][c] = 0.f;
  #pragma unroll
  for (int t = 0; t < NT; ++t) {
    const int n = (NT0 + t) * 16 + ln;
    if (n < HID) {
      const float bias = b1[n];
      const float2* w2r = (const float2*)(w2 + n * NCLS);
      float2 wv[5];
      #pragma unroll
      for (int p = 0; p < 5; ++p) wv[p] = w2r[p];
      #pragma unroll
      for (int rr = 0; rr < 4; ++rr) {
        const float hd = fmaxf(acc[t][rr] + bias, 0.f);
        #pragma unroll
        for (int p = 0; p < 5; ++p) {
          partial[rr][2 * p]     += hd * wv[p].x;
          partial[rr][2 * p + 1] += hd * wv[p].y;
        }
      }
    }
  }
  #pragma unroll
  for (int rr = 0; rr < 4; ++rr) {
    #pragma unroll
    for (int c = 0; c < NCLS; ++c) {
      float v = partial[rr][c];
      v += __shfl_xor(v, 1, 16);
      v += __shfl_xor(v, 2, 16);
      v += __shfl_xor(v, 4, 16);
      v += __shfl_xor(v, 8, 16);
      if (ln == 0) pbuf[wave][qd * 4 + rr][c] = v;
    }
  }
}

__global__ __launch_bounds__(256) void fused_fwd(
    const float* __restrict__ x, const float* __restrict__ cwp,
    const unsigned short* __restrict__ w1tf, const float* __restrict__ b1,
    const float* __restrict__ w2, const float* __restrict__ b2,
    float* __restrict__ out) {
  __shared__ unsigned short feat[FMT][FPAD];
  __shared__ float pbuf[4][FMT][NCLS];
  const int tid = threadIdx.x, wave = tid >> 6, lane = tid & 63;
  {
    unsigned int* fp = (unsigned int*)&feat[0][0];
    for (int i = tid; i < FMT * 18; i += 256) {
      int m = i / 18, d = i % 18;
      fp[m * (FPAD / 2) + 338 + d] = 0;
    }
  }
  float cw[9];
  #pragma unroll
  for (int t = 0; t < 9; ++t) cw[t] = cwp[t];
  for (int task = tid; task < FMT * OHW; task += 256) {
    int m = task & (FMT - 1);
    int i = task >> 4;
    const float4* xr = (const float4*)(x + ((size_t)blockIdx.x * FMT + m) * (HW * HW));
    float r[3][HW];
    #pragma unroll
    for (int di = 0; di < 3; ++di)
      #pragma unroll
      for (int q = 0; q < 7; ++q) {
        float4 v = xr[(i + di) * 7 + q];
        r[di][q * 4 + 0] = v.x; r[di][q * 4 + 1] = v.y;
        r[di][q * 4 + 2] = v.z; r[di][q * 4 + 3] = v.w;
      }
    unsigned int* dst = (unsigned int*)&feat[m][i * OHW];
    #pragma unroll
    for (int jp = 0; jp < 13; ++jp) {
      float s0 = 0.f, s1 = 0.f;
      #pragma unroll
      for (int di = 0; di < 3; ++di)
        #pragma unroll
        for (int dj = 0; dj < 3; ++dj) {
          s0 += cw[di * 3 + dj] * r[di][2 * jp + dj];
          s1 += cw[di * 3 + dj] * r[di][2 * jp + 1 + dj];
        }
      __hip_bfloat16 h0 = __float2bfloat16(s0);
      __hip_bfloat16 h1 = __float2bfloat16(s1);
      dst[jp] = (unsigned int)__builtin_bit_cast(unsigned short, h0)
              | ((unsigned int)__builtin_bit_cast(unsigned short, h1) << 16);
    }
  }
  __syncthreads();
  switch (wave) {
    case 0:  fgemm_epi<0, 4>(feat, w1tf, b1, w2, pbuf, wave, lane); break;
    case 1:  fgemm_epi<4, 3>(feat, w1tf, b1, w2, pbuf, wave, lane); break;
    case 2:  fgemm_epi<7, 3>(feat, w1tf, b1, w2, pbuf, wave, lane); break;
    default: fgemm_epi<10, 3>(feat, w1tf, b1, w2, pbuf, wave, lane); break;
  }
  __syncthreads();
  if (tid < FMT * NCLS) {
    int m = tid / NCLS, c = tid - m * NCLS;
    float s = pbuf[0][m][c] + pbuf[1][m][c] + pbuf[2][m][c] + pbuf[3][m][c] + b2[c];
    out[(size_t)blockIdx.x * (FMT * NCLS) + tid] = s;
  }
}

extern "C" void kernel_launch(void* const* d_in, const int* in_sizes, int n_in,
                              void* d_out, int out_size, void* d_ws, size_t ws_size,
                              hipStream_t stream) {
  const float* x  = (const float*)d_in[0];
  const float* cw = (const float*)d_in[1];
  const float* w1 = (const float*)d_in[2];
  const float* b1 = (const float*)d_in[3];
  const float* w2 = (const float*)d_in[4];
  const float* b2 = (const float*)d_in[5];
  float* out = (float*)d_out;

  unsigned short* w1tf = (unsigned short*)d_ws;          // 292,864 B
  const size_t feat_off = 524288;
  const size_t need = feat_off + (size_t)BATCH * FPAD * 2;  // ~93.8 MB

  hipLaunchKernelGGL(prep_w1tf, dim3(572), dim3(256), 0, stream, w1, w1tf);

  if (ws_size >= need) {
    unsigned short* featg = (unsigned short*)((char*)d_ws + feat_off);
    hipLaunchKernelGGL(conv_k, dim3(BATCH / CMT), dim3(256), 0, stream, x, cw, featg);
    hipLaunchKernelGGL(gemm_k, dim3(BATCH / GMT), dim3(256), 0, stream,
                       featg, w1tf, b1, w2, b2, out);
  } else {
    hipLaunchKernelGGL(fused_fwd, dim3(BATCH / FMT), dim3(256), 0, stream,
                       x, cw, w1tf, b1, w2, b2, out);
  }
}

// Round 5
// 357.526 us; speedup vs baseline: 1.6437x; 1.6437x over previous
//
#include <hip/hip_runtime.h>
#include <hip/hip_bf16.h>

// Problem constants
#define BATCH   65536
#define HW      28
#define OHW     26
#define FEAT    676      // 26*26
#define KPAD    704      // 22 chunks of 32 (GEMM1 K)
#define FPAD    712      // feat LDS row stride (ushorts): %8==0 for b128 align
#define HID     200
#define HPAD    224      // hidden LDS row stride (ushorts): 7 K-chunks of 32, %8==0
#define NCLS    10
#define MT      16       // images per block
#define NBLOCKS (BATCH / MT)   // 4096

typedef __attribute__((ext_vector_type(8))) __bf16 bf16x8;
typedef __attribute__((ext_vector_type(4))) float  f32x4;

__device__ __forceinline__ unsigned int pk2(float a, float b) {
  __hip_bfloat16 ha = __float2bfloat16(a), hb = __float2bfloat16(b);
  return (unsigned int)__builtin_bit_cast(unsigned short, ha)
       | ((unsigned int)__builtin_bit_cast(unsigned short, hb) << 16);
}

// ---------------------------------------------------------------------------
// prep_w1tf: w1 (676x200 f32) -> bf16 MFMA B-fragment order, coalesced reads.
// dst element ((kc*13+nt)*64 + qd*16 + ln)*8 + j  holds  w1[k][n],
//   n = nt*16+ln, k = kc*32+qd*8+j  (zero-padded)
// => each wave B-load in the GEMM is 64 lanes x 16B contiguous (1 KB).
// ---------------------------------------------------------------------------
__global__ __launch_bounds__(256) void prep_w1tf(const float* __restrict__ w1,
                                                 unsigned short* __restrict__ w1tf) {
  int idx = blockIdx.x * 256 + threadIdx.x;   // idx = k*208 + n
  if (idx >= 704 * 208) return;
  int k = idx / 208;
  int n = idx - k * 208;
  float v = (k < FEAT && n < HID) ? w1[k * HID + n] : 0.f;
  int nt = n >> 4, ln = n & 15;
  int kc = k >> 5, r = k & 31, qd = r >> 3, j = r & 7;
  size_t dst = ((size_t)(kc * 13 + nt) * 64 + qd * 16 + ln) * 8 + j;
  __hip_bfloat16 h = __float2bfloat16(v);
  w1tf[dst] = __builtin_bit_cast(unsigned short, h);
}

// w2 (200x10 f32) -> bf16 B-fragment order, K=224 N=16 padded. 7 KB.
__global__ __launch_bounds__(256) void prep_w2f(const float* __restrict__ w2,
                                                unsigned short* __restrict__ w2f) {
  int t = blockIdx.x * 256 + threadIdx.x;
  if (t >= 7 * 64 * 8) return;
  int j = t & 7, lane = (t >> 3) & 63, kc = t >> 9;
  int c = lane & 15;
  int k = kc * 32 + (lane >> 4) * 8 + j;
  float v = (c < NCLS && k < HID) ? w2[k * NCLS + c] : 0.f;
  __hip_bfloat16 h = __float2bfloat16(v);
  w2f[t] = __builtin_bit_cast(unsigned short, h);
}

// ---------------------------------------------------------------------------
// GEMM1 N-slice: 16x16x32 bf16 MFMA, A from LDS feat, B fragment-coalesced.
// C/D: col(n)=lane&15, row(m)=(lane>>4)*4+reg  [m89/m91 verified]
// Epilogue: relu(acc+b1) -> bf16 hidT[m][n] in LDS.
// ---------------------------------------------------------------------------
template<int NT0, int NT>
__device__ __forceinline__ void gemm1_slice(
    const unsigned short (*feat)[FPAD], const unsigned short* __restrict__ w1tf,
    const float* __restrict__ b1, unsigned short (*hidT)[HPAD], int ln, int qd) {
  f32x4 acc[NT];
  #pragma unroll
  for (int t = 0; t < NT; ++t) acc[t] = (f32x4){0.f, 0.f, 0.f, 0.f};
  const int koff = qd * 8;
  for (int kc = 0; kc < 22; ++kc) {
    bf16x8 a = *(const bf16x8*)&feat[ln][kc * 32 + koff];
    #pragma unroll
    for (int t = 0; t < NT; ++t) {
      bf16x8 b = *(const bf16x8*)(w1tf + ((size_t)(kc * 13 + NT0 + t) * 64 + qd * 16 + ln) * 8);
      acc[t] = __builtin_amdgcn_mfma_f32_16x16x32_bf16(a, b, acc[t], 0, 0, 0);
    }
  }
  #pragma unroll
  for (int t = 0; t < NT; ++t) {
    const int n = (NT0 + t) * 16 + ln;
    if (n < HID) {
      const float bias = b1[n];
      #pragma unroll
      for (int rr = 0; rr < 4; ++rr) {
        const int m = qd * 4 + rr;
        float h = fmaxf(acc[t][rr] + bias, 0.f);
        __hip_bfloat16 hb = __float2bfloat16(h);
        hidT[m][n] = __builtin_bit_cast(unsigned short, hb);
      }
    }
  }
}

__global__ __launch_bounds__(256, 3) void fused2(
    const float* __restrict__ x, const float* __restrict__ cwp,
    const unsigned short* __restrict__ w1tf, const unsigned short* __restrict__ w2f,
    const float* __restrict__ b1, const float* __restrict__ b2,
    float* __restrict__ out) {
  __shared__ float xs[4 * 784 + 8];             // 12,576 B (+8 guard for jc=6 tail reads)
  __shared__ unsigned short feat[MT][FPAD];     // 22,784 B
  __shared__ unsigned short hidT[MT][HPAD];     //  7,168 B  -> 42.6 KB total, 3 blk/CU
  const int tid  = threadIdx.x;
  const int wave = tid >> 6;
  const int lane = tid & 63;
  const int ln   = lane & 15;
  const int qd   = lane >> 4;

  // zero feat K-pad (cols 676..703 = dwords 338..351, 14 per row) — ALL rows
  for (int i = tid; i < MT * 14; i += 256) {
    int m = i / 14, d = i - m * 14;
    ((unsigned int*)&feat[0][0])[m * (FPAD / 2) + 338 + d] = 0u;
  }
  // zero hidT K-pad (cols 200..223 = dwords 100..111, 12 per row) — ALL rows
  // (R4 bug: this was tail-gated behind the feat loop and rows 3..15 kept
  //  garbage -> NaN*0 in the GEMM2 MFMA. Grid-stride fixes it.)
  for (int i = tid; i < MT * 12; i += 256) {
    int m = i / 12, d = i - m * 12;
    ((unsigned int*)&hidT[0][0])[m * (HPAD / 2) + 100 + d] = 0u;
  }

  float cw[9];
  #pragma unroll
  for (int t = 0; t < 9; ++t) cw[t] = cwp[t];

  // ---- conv: 4 phases x 4 images; wave w owns image 4p+w ----
  for (int p = 0; p < 4; ++p) {
    __syncthreads();   // xs reuse guard (and pad-zero guard on p=0)
    const float4* xg = (const float4*)x + ((size_t)blockIdx.x * MT + 4 * p) * 196;
    float4* xs4 = (float4*)xs;
    for (int idx = tid; idx < 784; idx += 256) xs4[idx] = xg[idx];
    __syncthreads();

    const int m = 4 * p + wave;
    const float* xw = xs + wave * 784;
    #pragma unroll
    for (int it = 0; it < 2; ++it) {
      const int t = it * 64 + lane;
      if (t < 91) {                       // 13 row-pairs x 7 col-quads
        const int iq = (t * 9363) >> 16;  // t/7 for t<91
        const int jc = t - 7 * iq;
        float in[4][6];
        #pragma unroll
        for (int rr = 0; rr < 4; ++rr) {
          const float* rp = xw + (2 * iq + rr) * HW + 4 * jc;
          float4 v = *(const float4*)rp;          // 16B aligned
          float2 u = *(const float2*)(rp + 4);    //  8B aligned (guard pad covers tail)
          in[rr][0] = v.x; in[rr][1] = v.y; in[rr][2] = v.z; in[rr][3] = v.w;
          in[rr][4] = u.x; in[rr][5] = u.y;
        }
        float o[2][4];
        #pragma unroll
        for (int dr = 0; dr < 2; ++dr)
          #pragma unroll
          for (int dc = 0; dc < 4; ++dc) {
            float s = 0.f;
            #pragma unroll
            for (int di = 0; di < 3; ++di)
              #pragma unroll
              for (int dj = 0; dj < 3; ++dj)
                s += cw[di * 3 + dj] * in[dr + di][dc + dj];
            o[dr][dc] = s;
          }
        unsigned short* fr = &feat[m][0];
        const int e0 = 52 * iq + 4 * jc;    // row 2iq, col 4jc (e0 % 4 == 0)
        if (jc < 6) {
          *(uint2*)&fr[e0] = make_uint2(pk2(o[0][0], o[0][1]), pk2(o[0][2], o[0][3]));
          *(unsigned int*)&fr[e0 + OHW]     = pk2(o[1][0], o[1][1]);
          *(unsigned int*)&fr[e0 + OHW + 2] = pk2(o[1][2], o[1][3]);
        } else {                            // cols 24,25 only
          *(unsigned int*)&fr[e0]       = pk2(o[0][0], o[0][1]);
          *(unsigned int*)&fr[e0 + OHW] = pk2(o[1][0], o[1][1]);
        }
      }
    }
  }
  __syncthreads();   // feat complete

  // ---- GEMM1: per-wave N-slice (13 tiles over 4 waves) ----
  switch (wave) {
    case 0:  gemm1_slice<0, 4>(feat, w1tf, b1, hidT, ln, qd); break;
    case 1:  gemm1_slice<4, 3>(feat, w1tf, b1, hidT, ln, qd); break;
    case 2:  gemm1_slice<7, 3>(feat, w1tf, b1, hidT, ln, qd); break;
    default: gemm1_slice<10, 3>(feat, w1tf, b1, hidT, ln, qd); break;
  }
  __syncthreads();   // hidT complete

  // ---- GEMM2: wave 0 only, one 16x16 MFMA tile over K=224 ----
  if (wave == 0) {
    f32x4 acc2 = (f32x4){0.f, 0.f, 0.f, 0.f};
    #pragma unroll
    for (int kc = 0; kc < 7; ++kc) {
      bf16x8 a = *(const bf16x8*)&hidT[ln][kc * 32 + qd * 8];
      bf16x8 b = *(const bf16x8*)(w2f + ((size_t)kc * 64 + lane) * 8);
      acc2 = __builtin_amdgcn_mfma_f32_16x16x32_bf16(a, b, acc2, 0, 0, 0);
    }
    if (ln < NCLS) {
      const float bb = b2[ln];
      #pragma unroll
      for (int rr = 0; rr < 4; ++rr) {
        const int m = qd * 4 + rr;
        out[((size_t)blockIdx.x * MT + m) * NCLS + ln] = acc2[rr] + bb;
      }
    }
  }
}

extern "C" void kernel_launch(void* const* d_in, const int* in_sizes, int n_in,
                              void* d_out, int out_size, void* d_ws, size_t ws_size,
                              hipStream_t stream) {
  const float* x  = (const float*)d_in[0];
  const float* cw = (const float*)d_in[1];
  const float* w1 = (const float*)d_in[2];
  const float* b1 = (const float*)d_in[3];
  const float* w2 = (const float*)d_in[4];
  const float* b2 = (const float*)d_in[5];
  float* out = (float*)d_out;

  unsigned short* w1tf = (unsigned short*)d_ws;                       // 292,864 B
  unsigned short* w2f  = (unsigned short*)((char*)d_ws + 294912);     //   7,168 B

  hipLaunchKernelGGL(prep_w1tf, dim3((704 * 208 + 255) / 256), dim3(256), 0, stream,
                     w1, w1tf);
  hipLaunchKernelGGL(prep_w2f, dim3(14), dim3(256), 0, stream, w2, w2f);
  hipLaunchKernelGGL(fused2, dim3(NBLOCKS), dim3(256), 0, stream,
                     x, cw, w1tf, w2f, b1, b2, out);
}